// Round 4
// baseline (426.023 us; speedup 1.0000x reference)
//
#include <hip/hip_runtime.h>

#define N_NODES 50000
#define N_EDGES 800000
#define F_NODE 128
#define F_EDGE 16

#define SCAN_B 256
#define NB1 ((N_NODES + SCAN_B - 1) / SCAN_B)   // 196 blocks

#define BUCK_SH 6                                // 64 nodes / bucket
#define NBUCK ((N_NODES + 63) >> BUCK_SH)        // 782
#define NPART 8                                  // blockIdx&7 ~ XCD
#define CAP_PART 304                             // slots per (bucket,part) cell

// ---------------- bf16 helpers (bf16 = top 16 bits of fp32, RNE) -----------
__device__ __forceinline__ unsigned int bf16_rn(float f) {
    unsigned int u = __float_as_uint(f);
    unsigned int r = ((u >> 16) & 1u) + 0x7fffu;
    return (u + r) >> 16;
}
__device__ __forceinline__ unsigned int pack_bf16(float a, float b) {
    return bf16_rn(a) | (bf16_rn(b) << 16);
}
__device__ __forceinline__ float bf_lo(unsigned int u) { return __uint_as_float(u << 16); }
__device__ __forceinline__ float bf_hi(unsigned int u) { return __uint_as_float(u & 0xffff0000u); }

// ---------------- convert x (N,128 fp32) -> packed bf16 pairs --------------
__global__ __launch_bounds__(256) void f32_to_bf16(const float4* __restrict__ in,
                                                   uint2* __restrict__ outp,
                                                   int n4) {
    int i = blockIdx.x * 256 + threadIdx.x;
    if (i >= n4) return;
    float4 v = in[i];
    uint2 o;
    o.x = pack_bf16(v.x, v.y);
    o.y = pack_bf16(v.z, v.w);
    outp[i] = o;
}

// ---------------- CSR build: histogram + scan ------------------------------
__global__ __launch_bounds__(256) void hist_dst(const int* __restrict__ dst,
                                                int* __restrict__ deg) {
    int e = blockIdx.x * 256 + threadIdx.x;
    if (e >= N_EDGES) return;
    atomicAdd(&deg[dst[e]], 1);
}

__global__ __launch_bounds__(256) void scan1(const int* __restrict__ deg,
                                             int* __restrict__ rs,
                                             int* __restrict__ bsum) {
    __shared__ int sh[SCAN_B];
    int i = blockIdx.x * SCAN_B + threadIdx.x;
    int v = (i < N_NODES) ? deg[i] : 0;
    sh[threadIdx.x] = v;
    __syncthreads();
    for (int off = 1; off < SCAN_B; off <<= 1) {
        int t = (threadIdx.x >= off) ? sh[threadIdx.x - off] : 0;
        __syncthreads();
        sh[threadIdx.x] += t;
        __syncthreads();
    }
    if (i < N_NODES) rs[i] = sh[threadIdx.x] - v;
    if (threadIdx.x == SCAN_B - 1) bsum[blockIdx.x] = sh[threadIdx.x];
}

__global__ __launch_bounds__(256) void scan2(const int* __restrict__ bsum,
                                             int* __restrict__ boff) {
    __shared__ int sh[SCAN_B];
    int v = (threadIdx.x < NB1) ? bsum[threadIdx.x] : 0;
    sh[threadIdx.x] = v;
    __syncthreads();
    for (int off = 1; off < SCAN_B; off <<= 1) {
        int t = (threadIdx.x >= off) ? sh[threadIdx.x - off] : 0;
        __syncthreads();
        sh[threadIdx.x] += t;
        __syncthreads();
    }
    boff[threadIdx.x] = sh[threadIdx.x] - v;
}

__global__ __launch_bounds__(256) void scan3(int* __restrict__ rs,
                                             const int* __restrict__ boff) {
    int i = blockIdx.x * 256 + threadIdx.x;
    if (i < N_NODES) rs[i] += boff[i >> 8];
    if (i == 0) rs[N_NODES] = N_EDGES;
}

// ---------------- CSR build pass 1: bucketed scatter -----------------------
// Edge -> (bucket = dst>>6, part = blockIdx&7) cell. Positions within a cell
// are sequential (atomic cursor) -> line-dense stores, single-XCD per cell.
// Payload packed: src (17b) | eid (20b) | dst_local (6b).
__global__ __launch_bounds__(256) void bucket_scatter(
    const int* __restrict__ src, const int* __restrict__ dst,
    int* __restrict__ bcur, unsigned long long* __restrict__ temp)
{
    int e = blockIdx.x * 256 + threadIdx.x;
    if (e >= N_EDGES) return;
    int d = dst[e];
    int b = d >> BUCK_SH;
    int dl = d & 63;
    int cell = b * NPART + (blockIdx.x & (NPART - 1));
    int pos = atomicAdd(&bcur[cell], 1);
    if (pos < CAP_PART)
        temp[(size_t)cell * CAP_PART + pos] =
            (unsigned long long)src[e] |
            ((unsigned long long)e  << 17) |
            ((unsigned long long)dl << 37);
}

// ---------------- CSR build pass 2: per-bucket permute ---------------------
// One workgroup per bucket. Reads the bucket's 8 cells, places entries into
// the bucket's contiguous CSR range via LDS per-node cursors. Writes hit an
// ~8KB L2-hot region -> dense writeback.
__global__ __launch_bounds__(256) void bucket_permute(
    const unsigned long long* __restrict__ temp,
    const int* __restrict__ bcur,
    const int* __restrict__ rs,
    int* __restrict__ csr_src, int* __restrict__ csr_eid)
{
    __shared__ int rs_l[65];
    __shared__ int cnt[64];
    int b = blockIdx.x;
    int node0 = b << BUCK_SH;
    int nn = min(64, N_NODES - node0);
    int tid = threadIdx.x;
    if (tid <= nn) rs_l[tid] = rs[node0 + tid];
    if (tid < 64) cnt[tid] = 0;
    __syncthreads();
    for (int part = 0; part < NPART; ++part) {
        int cell = b * NPART + part;
        int m = bcur[cell];
        if (m > CAP_PART) m = CAP_PART;
        size_t base = (size_t)cell * CAP_PART;
        for (int i = tid; i < m; i += 256) {
            unsigned long long v = temp[base + i];
            int s  = (int)(v & 0x1FFFF);
            int ei = (int)((v >> 17) & 0xFFFFF);
            int dl = (int)(v >> 37);
            int pos = rs_l[dl] + atomicAdd(&cnt[dl], 1);
            csr_src[pos] = s;
            csr_eid[pos] = ei;
        }
    }
}

// ---------------- node-feature aggregation (bf16 source) -------------------
// one wave per node; 64 lanes x 4B (2 bf16) = full 256B row; 4-edge unroll.
__global__ __launch_bounds__(256) void agg128_bf16(const unsigned int* __restrict__ xb,
                                                   const int* __restrict__ rs,
                                                   const int* __restrict__ csr_src,
                                                   float* __restrict__ xa) {
    int gid = blockIdx.x * 256 + threadIdx.x;
    int n = gid >> 6;
    int lane = threadIdx.x & 63;
    if (n >= N_NODES) return;
    int beg = rs[n], end = rs[n + 1];
    float a0 = 0.f, a1 = 0.f;
    int i = beg;
    for (; i + 4 <= end; i += 4) {
        int s0 = csr_src[i], s1 = csr_src[i + 1];
        int s2 = csr_src[i + 2], s3 = csr_src[i + 3];
        unsigned int u0 = xb[(size_t)s0 * 64 + lane];
        unsigned int u1 = xb[(size_t)s1 * 64 + lane];
        unsigned int u2 = xb[(size_t)s2 * 64 + lane];
        unsigned int u3 = xb[(size_t)s3 * 64 + lane];
        a0 += bf_lo(u0) + bf_lo(u1) + bf_lo(u2) + bf_lo(u3);
        a1 += bf_hi(u0) + bf_hi(u1) + bf_hi(u2) + bf_hi(u3);
    }
    for (; i < end; ++i) {
        unsigned int u = xb[(size_t)csr_src[i] * 64 + lane];
        a0 += bf_lo(u);
        a1 += bf_hi(u);
    }
    *(float2*)(xa + (size_t)n * F_NODE + lane * 2) = make_float2(a0, a1);
}

// ---------------- edge-attr aggregation ------------------------------------
// one wave per node; 4 subgroups x 16 lanes take every 4th edge; butterfly.
__global__ __launch_bounds__(256) void agg_feat16(const float* __restrict__ eattr,
                                                  const int* __restrict__ rs,
                                                  const int* __restrict__ csr_eid,
                                                  float* __restrict__ eagg) {
    int gid = blockIdx.x * 256 + threadIdx.x;
    int n = gid >> 6;
    int lane = threadIdx.x & 63;
    int sub = lane >> 4;
    int j = lane & 15;
    if (n >= N_NODES) return;
    int beg = rs[n], end = rs[n + 1];
    float acc = 0.f;
    for (int i = beg + sub; i < end; i += 4) {
        int eid = csr_eid[i];
        acc += eattr[(size_t)eid * F_EDGE + j];
    }
    acc += __shfl_xor(acc, 16, 64);
    acc += __shfl_xor(acc, 32, 64);
    if (sub == 0) eagg[(size_t)n * F_EDGE + j] = acc;
}

// ---------------- tiled fp32 GEMM ------------------------------------------
// out = [xa|eagg](N x 144) @ W(144x128) + b; optional fused-relu bf16 output.
// xa may alias out_f32 (d_out): each block reads its rows before writing them.
#define BM 64
#define BK 16
#define LDA (BM + 4)
#define LDB (128 + 4)

__global__ __launch_bounds__(256) void layer_gemm(
    const float* xa,
    const float* __restrict__ eagg,
    const float* __restrict__ W,
    const float* __restrict__ bias,
    float* out_f32,
    unsigned int* __restrict__ out_bf,
    int do_relu, int out_bf16)
{
    __shared__ float As[BK][LDA];
    __shared__ float Bs[BK][LDB];
    const int tid = threadIdx.x;
    const int bm = blockIdx.x * BM;

    const int tcol = (tid & 15) * 8;
    const int trow = (tid >> 4) * 4;

    const int lm = tid >> 2;
    const int lk = (tid & 3) * 4;
    const int bk = tid >> 4;
    const int bj = (tid & 15) * 8;

    const int row = bm + lm;
    const bool rowok = row < N_NODES;

    float acc[4][8];
    #pragma unroll
    for (int i = 0; i < 4; ++i)
        #pragma unroll
        for (int j = 0; j < 8; ++j) acc[i][j] = 0.f;

    for (int k0 = 0; k0 < 144; k0 += BK) {
        float4 av = make_float4(0.f, 0.f, 0.f, 0.f);
        if (rowok) {
            if (k0 < F_NODE)
                av = *(const float4*)(xa + (size_t)row * F_NODE + k0 + lk);
            else
                av = *(const float4*)(eagg + (size_t)row * F_EDGE + lk);
        }
        As[lk + 0][lm] = av.x;
        As[lk + 1][lm] = av.y;
        As[lk + 2][lm] = av.z;
        As[lk + 3][lm] = av.w;

        const float4 b0 = *(const float4*)(W + (size_t)(k0 + bk) * 128 + bj);
        const float4 b1 = *(const float4*)(W + (size_t)(k0 + bk) * 128 + bj + 4);
        *(float4*)(&Bs[bk][bj])     = b0;
        *(float4*)(&Bs[bk][bj + 4]) = b1;
        __syncthreads();

        #pragma unroll
        for (int k = 0; k < BK; ++k) {
            float a0 = As[k][trow + 0];
            float a1 = As[k][trow + 1];
            float a2 = As[k][trow + 2];
            float a3 = As[k][trow + 3];
            float bv[8];
            #pragma unroll
            for (int j = 0; j < 8; ++j) bv[j] = Bs[k][tcol + j];
            #pragma unroll
            for (int j = 0; j < 8; ++j) {
                acc[0][j] = fmaf(a0, bv[j], acc[0][j]);
                acc[1][j] = fmaf(a1, bv[j], acc[1][j]);
                acc[2][j] = fmaf(a2, bv[j], acc[2][j]);
                acc[3][j] = fmaf(a3, bv[j], acc[3][j]);
            }
        }
        __syncthreads();
    }

    float4 bb0 = *(const float4*)(bias + tcol);
    float4 bb1 = *(const float4*)(bias + tcol + 4);
    #pragma unroll
    for (int i = 0; i < 4; ++i) {
        int r = bm + trow + i;
        if (r >= N_NODES) break;
        float v[8];
        v[0] = acc[i][0] + bb0.x; v[1] = acc[i][1] + bb0.y;
        v[2] = acc[i][2] + bb0.z; v[3] = acc[i][3] + bb0.w;
        v[4] = acc[i][4] + bb1.x; v[5] = acc[i][5] + bb1.y;
        v[6] = acc[i][6] + bb1.z; v[7] = acc[i][7] + bb1.w;
        if (do_relu) {
            #pragma unroll
            for (int j = 0; j < 8; ++j) v[j] = fmaxf(v[j], 0.f);
        }
        if (out_bf16) {
            uint4 s;
            s.x = pack_bf16(v[0], v[1]);
            s.y = pack_bf16(v[2], v[3]);
            s.z = pack_bf16(v[4], v[5]);
            s.w = pack_bf16(v[6], v[7]);
            *(uint4*)(out_bf + (size_t)r * 64 + tcol / 2) = s;
        } else {
            *(float4*)(out_f32 + (size_t)r * 128 + tcol)     = make_float4(v[0], v[1], v[2], v[3]);
            *(float4*)(out_f32 + (size_t)r * 128 + tcol + 4) = make_float4(v[4], v[5], v[6], v[7]);
        }
    }
}

// ---------------------------------------------------------------------------
extern "C" void kernel_launch(void* const* d_in, const int* in_sizes, int n_in,
                              void* d_out, int out_size, void* d_ws, size_t ws_size,
                              hipStream_t stream) {
    const float* x     = (const float*)d_in[0];   // (50000,128)
    const int*   eidx  = (const int*)  d_in[1];   // (2,800000)
    const float* eattr = (const float*)d_in[2];   // (800000,16)
    const float* W1    = (const float*)d_in[3];   // (144,128)
    const float* b1    = (const float*)d_in[4];
    const float* W2    = (const float*)d_in[5];   // (144,128)
    const float* b2    = (const float*)d_in[6];
    float* out = (float*)d_out;                   // (50000,128)

    const int* srcv = eidx;
    const int* dstv = eidx + N_EDGES;

    // ws layout (~22.9 MB). regionA (16 MB) is time-shared:
    //   [bucket_scatter .. bucket_permute]  : temp (15.2 MB)
    //   [f32_to_bf16 .. end]                : xbhb (12.8 MB) | eagg (3.2 MB)
    char* p = (char*)d_ws;
    char* regionA = p;                      p += (size_t)16 * 1024 * 1024;
    int* csr_src  = (int*)p;                p += (size_t)N_EDGES * 4;
    int* csr_eid  = (int*)p;                p += (size_t)N_EDGES * 4;
    int* rs       = (int*)p;                p += (size_t)(N_NODES + 1) * 4;
    int* deg      = (int*)p;                p += (size_t)N_NODES * 4;      // deg+bcur contiguous
    int* bcur     = (int*)p;                p += (size_t)NBUCK * NPART * 4;
    int* bsum     = (int*)p;                p += 256 * 4;
    int* boff     = (int*)p;

    unsigned long long* temp = (unsigned long long*)regionA;
    unsigned int* xbhb = (unsigned int*)regionA;
    float* eagg = (float*)(regionA + (size_t)N_NODES * 64 * 4);

    float* xa = out;   // aggregated features live in d_out (see layer_gemm note)

    // zero deg + bcur (contiguous)
    hipMemsetAsync(deg, 0, ((size_t)N_NODES + (size_t)NBUCK * NPART) * 4, stream);

    // CSR build
    hist_dst<<<(N_EDGES + 255) / 256, 256, 0, stream>>>(dstv, deg);
    scan1<<<NB1, SCAN_B, 0, stream>>>(deg, rs, bsum);
    scan2<<<1, SCAN_B, 0, stream>>>(bsum, boff);
    scan3<<<NB1, SCAN_B, 0, stream>>>(rs, boff);
    bucket_scatter<<<(N_EDGES + 255) / 256, 256, 0, stream>>>(srcv, dstv, bcur, temp);
    bucket_permute<<<NBUCK, 256, 0, stream>>>(temp, bcur, rs, csr_src, csr_eid);

    // temp dead; xbhb/eagg live from here
    f32_to_bf16<<<(N_NODES * 32 + 255) / 256, 256, 0, stream>>>(
        (const float4*)x, (uint2*)xbhb, N_NODES * 32);

    agg_feat16<<<(N_NODES * 64 + 255) / 256, 256, 0, stream>>>(eattr, rs, csr_eid, eagg);

    // layer 1
    agg128_bf16<<<(N_NODES * 64 + 255) / 256, 256, 0, stream>>>(xbhb, rs, csr_src, xa);
    layer_gemm<<<(N_NODES + BM - 1) / BM, 256, 0, stream>>>(
        xa, eagg, W1, b1, (float*)nullptr, xbhb, 1, 1);

    // layer 2
    agg128_bf16<<<(N_NODES * 64 + 255) / 256, 256, 0, stream>>>(xbhb, rs, csr_src, xa);
    layer_gemm<<<(N_NODES + BM - 1) / BM, 256, 0, stream>>>(
        xa, eagg, W2, b2, out, (unsigned int*)nullptr, 0, 0);
}

// Round 5
// 361.769 us; speedup vs baseline: 1.1776x; 1.1776x over previous
//
#include <hip/hip_runtime.h>

#define N_NODES 50000
#define N_EDGES 800000
#define F_NODE 128
#define F_EDGE 16

#define SCAN_B 256
#define NB1 ((N_NODES + SCAN_B - 1) / SCAN_B)   // 196 blocks

#define BUCK_SH 6                                // 64 nodes / bucket
#define NBUCK ((N_NODES + 63) >> BUCK_SH)        // 782
#define NPART 8                                  // blockIdx&7 ~ XCD
#define CAP_PART 304                             // slots per (bucket,part) cell
#define BCUR_STRIDE 16                           // 1 cursor per 64B line

// ---------------- bf16 helpers (bf16 = top 16 bits of fp32, RNE) -----------
__device__ __forceinline__ unsigned int bf16_rn(float f) {
    unsigned int u = __float_as_uint(f);
    unsigned int r = ((u >> 16) & 1u) + 0x7fffu;
    return (u + r) >> 16;
}
__device__ __forceinline__ unsigned int pack_bf16(float a, float b) {
    return bf16_rn(a) | (bf16_rn(b) << 16);
}
__device__ __forceinline__ float bf_lo(unsigned int u) { return __uint_as_float(u << 16); }
__device__ __forceinline__ float bf_hi(unsigned int u) { return __uint_as_float(u & 0xffff0000u); }

// ---------------- convert x (N,128 fp32) -> packed bf16 pairs --------------
__global__ __launch_bounds__(256) void f32_to_bf16(const float4* __restrict__ in,
                                                   uint2* __restrict__ outp,
                                                   int n4) {
    int i = blockIdx.x * 256 + threadIdx.x;
    if (i >= n4) return;
    float4 v = in[i];
    uint2 o;
    o.x = pack_bf16(v.x, v.y);
    o.y = pack_bf16(v.z, v.w);
    outp[i] = o;
}

// ---------------- CSR build: histogram + scan ------------------------------
__global__ __launch_bounds__(256) void hist_dst(const int* __restrict__ dst,
                                                int* __restrict__ deg) {
    int e = blockIdx.x * 256 + threadIdx.x;
    if (e >= N_EDGES) return;
    atomicAdd(&deg[dst[e]], 1);
}

__global__ __launch_bounds__(256) void scan1(const int* __restrict__ deg,
                                             int* __restrict__ rs,
                                             int* __restrict__ bsum) {
    __shared__ int sh[SCAN_B];
    int i = blockIdx.x * SCAN_B + threadIdx.x;
    int v = (i < N_NODES) ? deg[i] : 0;
    sh[threadIdx.x] = v;
    __syncthreads();
    for (int off = 1; off < SCAN_B; off <<= 1) {
        int t = (threadIdx.x >= off) ? sh[threadIdx.x - off] : 0;
        __syncthreads();
        sh[threadIdx.x] += t;
        __syncthreads();
    }
    if (i < N_NODES) rs[i] = sh[threadIdx.x] - v;
    if (threadIdx.x == SCAN_B - 1) bsum[blockIdx.x] = sh[threadIdx.x];
}

__global__ __launch_bounds__(256) void scan2(const int* __restrict__ bsum,
                                             int* __restrict__ boff) {
    __shared__ int sh[SCAN_B];
    int v = (threadIdx.x < NB1) ? bsum[threadIdx.x] : 0;
    sh[threadIdx.x] = v;
    __syncthreads();
    for (int off = 1; off < SCAN_B; off <<= 1) {
        int t = (threadIdx.x >= off) ? sh[threadIdx.x - off] : 0;
        __syncthreads();
        sh[threadIdx.x] += t;
        __syncthreads();
    }
    boff[threadIdx.x] = sh[threadIdx.x] - v;
}

__global__ __launch_bounds__(256) void scan3(int* __restrict__ rs,
                                             const int* __restrict__ boff) {
    int i = blockIdx.x * 256 + threadIdx.x;
    if (i < N_NODES) rs[i] += boff[i >> 8];
    if (i == 0) rs[N_NODES] = N_EDGES;
}

// ---------------- CSR build pass 1: bucketed scatter -----------------------
// Edge -> (bucket = dst>>6, part = blockIdx&7) cell. One cursor per 64B line
// (BCUR_STRIDE) so atomic line contention is 128 ops/line, not 2048.
// Payload packed: src (17b) | eid (20b) | dst_local (6b).
__global__ __launch_bounds__(256) void bucket_scatter(
    const int* __restrict__ src, const int* __restrict__ dst,
    int* __restrict__ bcur, unsigned long long* __restrict__ temp)
{
    int e = blockIdx.x * 256 + threadIdx.x;
    if (e >= N_EDGES) return;
    int d = dst[e];
    int b = d >> BUCK_SH;
    int dl = d & 63;
    int cell = b * NPART + (blockIdx.x & (NPART - 1));
    int pos = atomicAdd(&bcur[cell * BCUR_STRIDE], 1);
    if (pos < CAP_PART)
        temp[(size_t)cell * CAP_PART + pos] =
            (unsigned long long)src[e] |
            ((unsigned long long)e  << 17) |
            ((unsigned long long)dl << 37);
}

// ---------------- CSR build pass 2: per-bucket permute ---------------------
// One workgroup per bucket; places entries into the bucket's contiguous CSR
// range via LDS per-node cursors (writes hit an ~8KB L2-hot region).
__global__ __launch_bounds__(256) void bucket_permute(
    const unsigned long long* __restrict__ temp,
    const int* __restrict__ bcur,
    const int* __restrict__ rs,
    int* __restrict__ csr_src, int* __restrict__ csr_eid)
{
    __shared__ int rs_l[65];
    __shared__ int cnt[64];
    int b = blockIdx.x;
    int node0 = b << BUCK_SH;
    int nn = min(64, N_NODES - node0);
    int tid = threadIdx.x;
    if (tid <= nn) rs_l[tid] = rs[node0 + tid];
    if (tid < 64) cnt[tid] = 0;
    __syncthreads();
    for (int part = 0; part < NPART; ++part) {
        int cell = b * NPART + part;
        int m = bcur[cell * BCUR_STRIDE];
        if (m > CAP_PART) m = CAP_PART;
        size_t base = (size_t)cell * CAP_PART;
        for (int i = tid; i < m; i += 256) {
            unsigned long long v = temp[base + i];
            int s  = (int)(v & 0x1FFFF);
            int ei = (int)((v >> 17) & 0xFFFFF);
            int dl = (int)(v >> 37);
            int pos = rs_l[dl] + atomicAdd(&cnt[dl], 1);
            csr_src[pos] = s;
            csr_eid[pos] = ei;
        }
    }
}

// ---------------- node-feature aggregation (bf16 source) -------------------
// one wave per node; 64 lanes x 4B (2 bf16) = full 256B row; 8-row unroll
// for deep MLP.
__global__ __launch_bounds__(256) void agg128_bf16(const unsigned int* __restrict__ xb,
                                                   const int* __restrict__ rs,
                                                   const int* __restrict__ csr_src,
                                                   float* __restrict__ xa) {
    int gid = blockIdx.x * 256 + threadIdx.x;
    int n = gid >> 6;
    int lane = threadIdx.x & 63;
    if (n >= N_NODES) return;
    int beg = rs[n], end = rs[n + 1];
    float a0 = 0.f, a1 = 0.f;
    int i = beg;
    for (; i + 8 <= end; i += 8) {
        int s[8];
        #pragma unroll
        for (int t = 0; t < 8; ++t) s[t] = csr_src[i + t];
        unsigned int u[8];
        #pragma unroll
        for (int t = 0; t < 8; ++t) u[t] = xb[(size_t)s[t] * 64 + lane];
        #pragma unroll
        for (int t = 0; t < 8; ++t) { a0 += bf_lo(u[t]); a1 += bf_hi(u[t]); }
    }
    for (; i + 4 <= end; i += 4) {
        int s[4];
        #pragma unroll
        for (int t = 0; t < 4; ++t) s[t] = csr_src[i + t];
        unsigned int u[4];
        #pragma unroll
        for (int t = 0; t < 4; ++t) u[t] = xb[(size_t)s[t] * 64 + lane];
        #pragma unroll
        for (int t = 0; t < 4; ++t) { a0 += bf_lo(u[t]); a1 += bf_hi(u[t]); }
    }
    for (; i < end; ++i) {
        unsigned int u = xb[(size_t)csr_src[i] * 64 + lane];
        a0 += bf_lo(u);
        a1 += bf_hi(u);
    }
    *(float2*)(xa + (size_t)n * F_NODE + lane * 2) = make_float2(a0, a1);
}

// ---------------- edge-attr aggregation ------------------------------------
// one wave per node; 16 subgroups x 4 lanes x float4 -> 16 outstanding 64B
// row fetches per wave (HBM-latency-bound gather); butterfly reduce.
__global__ __launch_bounds__(256) void agg_feat16(const float4* __restrict__ eattr4,
                                                  const int* __restrict__ rs,
                                                  const int* __restrict__ csr_eid,
                                                  float* __restrict__ eagg) {
    int gid = blockIdx.x * 256 + threadIdx.x;
    int n = gid >> 6;
    int lane = threadIdx.x & 63;
    int sub = lane >> 2;       // 0..15
    int j4  = lane & 3;        // float4 slot within the 16-float row
    if (n >= N_NODES) return;
    int beg = rs[n], end = rs[n + 1];
    float4 acc = make_float4(0.f, 0.f, 0.f, 0.f);
    for (int i = beg + sub; i < end; i += 16) {
        int eid = csr_eid[i];
        float4 v = eattr4[(size_t)eid * 4 + j4];
        acc.x += v.x; acc.y += v.y; acc.z += v.z; acc.w += v.w;
    }
    #pragma unroll
    for (int m = 4; m <= 32; m <<= 1) {
        acc.x += __shfl_xor(acc.x, m, 64);
        acc.y += __shfl_xor(acc.y, m, 64);
        acc.z += __shfl_xor(acc.z, m, 64);
        acc.w += __shfl_xor(acc.w, m, 64);
    }
    if (sub == 0) *(float4*)(eagg + (size_t)n * F_EDGE + j4 * 4) = acc;
}

// ---------------- tiled fp32 GEMM ------------------------------------------
// out = [xa|eagg](N x 144) @ W(144x128) + b; optional fused-relu bf16 output.
// xa may alias out_f32 (d_out): each block reads its rows before writing them.
#define BM 64
#define BK 16
#define LDA (BM + 4)
#define LDB (128 + 4)

__global__ __launch_bounds__(256) void layer_gemm(
    const float* xa,
    const float* __restrict__ eagg,
    const float* __restrict__ W,
    const float* __restrict__ bias,
    float* out_f32,
    unsigned int* __restrict__ out_bf,
    int do_relu, int out_bf16)
{
    __shared__ float As[BK][LDA];
    __shared__ float Bs[BK][LDB];
    const int tid = threadIdx.x;
    const int bm = blockIdx.x * BM;

    const int tcol = (tid & 15) * 8;
    const int trow = (tid >> 4) * 4;

    const int lm = tid >> 2;
    const int lk = (tid & 3) * 4;
    const int bk = tid >> 4;
    const int bj = (tid & 15) * 8;

    const int row = bm + lm;
    const bool rowok = row < N_NODES;

    float acc[4][8];
    #pragma unroll
    for (int i = 0; i < 4; ++i)
        #pragma unroll
        for (int j = 0; j < 8; ++j) acc[i][j] = 0.f;

    for (int k0 = 0; k0 < 144; k0 += BK) {
        float4 av = make_float4(0.f, 0.f, 0.f, 0.f);
        if (rowok) {
            if (k0 < F_NODE)
                av = *(const float4*)(xa + (size_t)row * F_NODE + k0 + lk);
            else
                av = *(const float4*)(eagg + (size_t)row * F_EDGE + lk);
        }
        As[lk + 0][lm] = av.x;
        As[lk + 1][lm] = av.y;
        As[lk + 2][lm] = av.z;
        As[lk + 3][lm] = av.w;

        const float4 b0 = *(const float4*)(W + (size_t)(k0 + bk) * 128 + bj);
        const float4 b1 = *(const float4*)(W + (size_t)(k0 + bk) * 128 + bj + 4);
        *(float4*)(&Bs[bk][bj])     = b0;
        *(float4*)(&Bs[bk][bj + 4]) = b1;
        __syncthreads();

        #pragma unroll
        for (int k = 0; k < BK; ++k) {
            float a0 = As[k][trow + 0];
            float a1 = As[k][trow + 1];
            float a2 = As[k][trow + 2];
            float a3 = As[k][trow + 3];
            float bv[8];
            #pragma unroll
            for (int j = 0; j < 8; ++j) bv[j] = Bs[k][tcol + j];
            #pragma unroll
            for (int j = 0; j < 8; ++j) {
                acc[0][j] = fmaf(a0, bv[j], acc[0][j]);
                acc[1][j] = fmaf(a1, bv[j], acc[1][j]);
                acc[2][j] = fmaf(a2, bv[j], acc[2][j]);
                acc[3][j] = fmaf(a3, bv[j], acc[3][j]);
            }
        }
        __syncthreads();
    }

    float4 bb0 = *(const float4*)(bias + tcol);
    float4 bb1 = *(const float4*)(bias + tcol + 4);
    #pragma unroll
    for (int i = 0; i < 4; ++i) {
        int r = bm + trow + i;
        if (r >= N_NODES) break;
        float v[8];
        v[0] = acc[i][0] + bb0.x; v[1] = acc[i][1] + bb0.y;
        v[2] = acc[i][2] + bb0.z; v[3] = acc[i][3] + bb0.w;
        v[4] = acc[i][4] + bb1.x; v[5] = acc[i][5] + bb1.y;
        v[6] = acc[i][6] + bb1.z; v[7] = acc[i][7] + bb1.w;
        if (do_relu) {
            #pragma unroll
            for (int j = 0; j < 8; ++j) v[j] = fmaxf(v[j], 0.f);
        }
        if (out_bf16) {
            uint4 s;
            s.x = pack_bf16(v[0], v[1]);
            s.y = pack_bf16(v[2], v[3]);
            s.z = pack_bf16(v[4], v[5]);
            s.w = pack_bf16(v[6], v[7]);
            *(uint4*)(out_bf + (size_t)r * 64 + tcol / 2) = s;
        } else {
            *(float4*)(out_f32 + (size_t)r * 128 + tcol)     = make_float4(v[0], v[1], v[2], v[3]);
            *(float4*)(out_f32 + (size_t)r * 128 + tcol + 4) = make_float4(v[4], v[5], v[6], v[7]);
        }
    }
}

// ---------------------------------------------------------------------------
extern "C" void kernel_launch(void* const* d_in, const int* in_sizes, int n_in,
                              void* d_out, int out_size, void* d_ws, size_t ws_size,
                              hipStream_t stream) {
    const float* x     = (const float*)d_in[0];   // (50000,128)
    const int*   eidx  = (const int*)  d_in[1];   // (2,800000)
    const float* eattr = (const float*)d_in[2];   // (800000,16)
    const float* W1    = (const float*)d_in[3];   // (144,128)
    const float* b1    = (const float*)d_in[4];
    const float* W2    = (const float*)d_in[5];   // (144,128)
    const float* b2    = (const float*)d_in[6];
    float* out = (float*)d_out;                   // (50000,128)

    const int* srcv = eidx;
    const int* dstv = eidx + N_EDGES;

    // ws layout (~23.5 MB). regionA (16 MB) is time-shared:
    //   [bucket_scatter .. bucket_permute]  : temp (15.2 MB)
    //   [f32_to_bf16 .. end]                : xbhb (12.8 MB) | eagg (3.2 MB)
    char* p = (char*)d_ws;
    char* regionA = p;                      p += (size_t)16 * 1024 * 1024;
    int* csr_src  = (int*)p;                p += (size_t)N_EDGES * 4;
    int* csr_eid  = (int*)p;                p += (size_t)N_EDGES * 4;
    int* rs       = (int*)p;                p += (size_t)(N_NODES + 1) * 4;
    int* deg      = (int*)p;                p += (size_t)N_NODES * 4;      // deg+bcur contiguous
    int* bcur     = (int*)p;                p += (size_t)NBUCK * NPART * BCUR_STRIDE * 4;
    int* bsum     = (int*)p;                p += 256 * 4;
    int* boff     = (int*)p;

    unsigned long long* temp = (unsigned long long*)regionA;
    unsigned int* xbhb = (unsigned int*)regionA;
    float* eagg = (float*)(regionA + (size_t)N_NODES * 64 * 4);

    float* xa = out;   // aggregated features live in d_out (see layer_gemm note)

    // zero deg + padded bcur (contiguous)
    hipMemsetAsync(deg, 0,
                   ((size_t)N_NODES + (size_t)NBUCK * NPART * BCUR_STRIDE) * 4,
                   stream);

    // CSR build
    hist_dst<<<(N_EDGES + 255) / 256, 256, 0, stream>>>(dstv, deg);
    scan1<<<NB1, SCAN_B, 0, stream>>>(deg, rs, bsum);
    scan2<<<1, SCAN_B, 0, stream>>>(bsum, boff);
    scan3<<<NB1, SCAN_B, 0, stream>>>(rs, boff);
    bucket_scatter<<<(N_EDGES + 255) / 256, 256, 0, stream>>>(srcv, dstv, bcur, temp);
    bucket_permute<<<NBUCK, 256, 0, stream>>>(temp, bcur, rs, csr_src, csr_eid);

    // temp dead; xbhb/eagg live from here
    f32_to_bf16<<<(N_NODES * 32 + 255) / 256, 256, 0, stream>>>(
        (const float4*)x, (uint2*)xbhb, N_NODES * 32);

    agg_feat16<<<(N_NODES * 64 + 255) / 256, 256, 0, stream>>>(
        (const float4*)eattr, rs, csr_eid, eagg);

    // layer 1
    agg128_bf16<<<(N_NODES * 64 + 255) / 256, 256, 0, stream>>>(xbhb, rs, csr_src, xa);
    layer_gemm<<<(N_NODES + BM - 1) / BM, 256, 0, stream>>>(
        xa, eagg, W1, b1, (float*)nullptr, xbhb, 1, 1);

    // layer 2
    agg128_bf16<<<(N_NODES * 64 + 255) / 256, 256, 0, stream>>>(xbhb, rs, csr_src, xa);
    layer_gemm<<<(N_NODES + BM - 1) / BM, 256, 0, stream>>>(
        xa, eagg, W2, b2, out, (unsigned int*)nullptr, 0, 0);
}